// Round 1
// baseline (435.160 us; speedup 1.0000x reference)
//
#include <hip/hip_runtime.h>
#include <math.h>

// ---------------------------------------------------------------------------
// Deformable transformer layer, MI355X round-0 baseline.
// B=2, Nq=8192, C=256, HEADS=8, dh=32, LEVELS=3, POINTS=4, MLP=4
// shapes (60,80),(30,40),(15,20), starts 0,4800,6000, Nv=6300
// ---------------------------------------------------------------------------

typedef short short8 __attribute__((ext_vector_type(8)));
typedef __bf16 bf16x8 __attribute__((ext_vector_type(8)));
typedef float f32x4 __attribute__((ext_vector_type(4)));

__device__ __forceinline__ short f2b(float f) {
  unsigned u = __builtin_bit_cast(unsigned, f);
  u += 0x7fffu + ((u >> 16) & 1u);   // RNE to bf16
  return (short)(u >> 16);
}

__device__ __forceinline__ f32x4 mfma16(short8 a, short8 b, f32x4 c) {
  return __builtin_amdgcn_mfma_f32_16x16x32_bf16(
      __builtin_bit_cast(bf16x8, a), __builtin_bit_cast(bf16x8, b), c, 0, 0, 0);
}

// ---------------------------------------------------------------------------
// LayerNorm: one wave per row of 256. Optionally writes y2 = y + pos.
// ---------------------------------------------------------------------------
__global__ __launch_bounds__(256) void ln_kernel(
    const float* __restrict__ x, const float* __restrict__ pos,
    const float* __restrict__ g, const float* __restrict__ bta,
    float* __restrict__ y, float* __restrict__ y2)
{
  const int row  = blockIdx.x * 4 + (threadIdx.x >> 6);
  const int lane = threadIdx.x & 63;
  const float4 v = ((const float4*)(x + (size_t)row * 256))[lane];
  float s = v.x + v.y + v.z + v.w;
#pragma unroll
  for (int o = 32; o; o >>= 1) s += __shfl_xor(s, o);
  const float mean = s * (1.f / 256.f);
  const float dx = v.x - mean, dy = v.y - mean, dz = v.z - mean, dw = v.w - mean;
  float s2 = dx * dx + dy * dy + dz * dz + dw * dw;
#pragma unroll
  for (int o = 32; o; o >>= 1) s2 += __shfl_xor(s2, o);
  const float inv = rsqrtf(s2 * (1.f / 256.f) + 1e-5f);
  const float4 gv = ((const float4*)g)[lane];
  const float4 bv = ((const float4*)bta)[lane];
  const float4 o1 = make_float4(dx * inv * gv.x + bv.x, dy * inv * gv.y + bv.y,
                                dz * inv * gv.z + bv.z, dw * inv * gv.w + bv.w);
  ((float4*)(y + (size_t)row * 256))[lane] = o1;
  if (pos != nullptr) {
    const float4 pv = ((const float4*)(pos + (size_t)row * 256))[lane];
    ((float4*)(y2 + (size_t)row * 256))[lane] =
        make_float4(o1.x + pv.x, o1.y + pv.y, o1.z + pv.z, o1.w + pv.w);
  }
}

// ---------------------------------------------------------------------------
// bf16-MFMA GEMM: C[M,N] = A[M,K] @ B[K,N] + bias (+ epilogue)
// EPI 0: none | 1: exact gelu | 2: += add1 + add2 | 3: += add1
// Tile 64x64, BK=32, 256 threads (4 waves, each 16 rows x 64 cols).
// ---------------------------------------------------------------------------
#define LSTR 40  // padded LDS row stride (bf16 elems); 80 B keeps 16 B alignment

template <int EPI>
__global__ __launch_bounds__(256) void gemm_kernel(
    const float* __restrict__ A, const float* __restrict__ Bw,
    const float* __restrict__ bias,
    const float* __restrict__ add1, const float* __restrict__ add2,
    float* __restrict__ C, int M, int N, int K)
{
  __shared__ short lA[64 * LSTR];
  __shared__ short lB[64 * LSTR];  // transposed: lB[n][k]

  const int t = threadIdx.x;
  const int wave = t >> 6, lane = t & 63;
  const int quad = lane >> 4, l16 = lane & 15;
  const int m0 = blockIdx.y * 64, n0 = blockIdx.x * 64;

  f32x4 acc[4];
#pragma unroll
  for (int s = 0; s < 4; s++) acc[s] = (f32x4){0.f, 0.f, 0.f, 0.f};

  // A staging: thread covers 8 consecutive k at (ar, ac)
  const int aid = t * 8;
  const int ar = aid >> 5, ac = aid & 31;
  const int agm = m0 + ar;
  // B staging: thread covers col bc, rows br0..br0+7, written transposed
  const int bc = t & 63;
  const int br0 = (t >> 6) * 8;
  const int bgn = n0 + bc;

  for (int k0 = 0; k0 < K; k0 += 32) {
    short8 av;
    if (agm < M) {
      const float* ap = A + (size_t)agm * K + (k0 + ac);
#pragma unroll
      for (int j = 0; j < 8; j++) av[j] = f2b(ap[j]);
    } else {
#pragma unroll
      for (int j = 0; j < 8; j++) av[j] = 0;
    }
    short8 bv;
    if (bgn < N) {
      const float* bp = Bw + (size_t)(k0 + br0) * N + bgn;
#pragma unroll
      for (int j = 0; j < 8; j++) bv[j] = f2b(bp[(size_t)j * N]);
    } else {
#pragma unroll
      for (int j = 0; j < 8; j++) bv[j] = 0;
    }
    *(short8*)&lA[ar * LSTR + ac] = av;
    *(short8*)&lB[bc * LSTR + br0] = bv;
    __syncthreads();

    const short8 af = *(const short8*)&lA[(wave * 16 + l16) * LSTR + quad * 8];
#pragma unroll
    for (int s = 0; s < 4; s++) {
      const short8 bf = *(const short8*)&lB[(s * 16 + l16) * LSTR + quad * 8];
      acc[s] = mfma16(af, bf, acc[s]);
    }
    __syncthreads();
  }

  const int rbase = wave * 16 + quad * 4;
#pragma unroll
  for (int s = 0; s < 4; s++) {
    const int gn = n0 + s * 16 + l16;
    if (gn >= N) continue;
    const float bb = bias[gn];
#pragma unroll
    for (int r = 0; r < 4; r++) {
      const int gm = m0 + rbase + r;
      if (gm >= M) continue;
      float val = acc[s][r] + bb;
      if (EPI == 1) val = 0.5f * val * (1.f + erff(val * 0.70710678118654752f));
      else if (EPI == 2) val += add1[(size_t)gm * N + gn] + add2[(size_t)gm * N + gn];
      else if (EPI == 3) val += add1[(size_t)gm * N + gn];
      C[(size_t)gm * N + gn] = val;
    }
  }
}

// ---------------------------------------------------------------------------
// Softmax over the 12 (= LEVELS*POINTS) logits of each (b,q,h), in place.
// ---------------------------------------------------------------------------
__global__ __launch_bounds__(256) void softmax12(float* __restrict__ aw)
{
  const int g = blockIdx.x * 256 + threadIdx.x;  // 131072 groups
  float* p = aw + (size_t)g * 12;
  float mx = p[0];
#pragma unroll
  for (int i = 1; i < 12; i++) mx = fmaxf(mx, p[i]);
  float e[12], sum = 0.f;
#pragma unroll
  for (int i = 0; i < 12; i++) { e[i] = __expf(p[i] - mx); sum += e[i]; }
  const float inv = 1.f / sum;
#pragma unroll
  for (int i = 0; i < 12; i++) p[i] = e[i] * inv;
}

// ---------------------------------------------------------------------------
// Deformable sampling: 32 lanes = one (b,q,h); lane d covers channel d of dh.
// v: [B, Nv, 256] (col = h*32+d), out: [B*Nq, 256]
// ---------------------------------------------------------------------------
__device__ __forceinline__ float vfetch(const float* __restrict__ vl,
                                        int x, int y, int W, int H)
{
  if (x < 0 || x >= W || y < 0 || y >= H) return 0.f;
  return vl[(size_t)(y * W + x) * 256];
}

__global__ __launch_bounds__(256) void deform_sample(
    const float* __restrict__ v, const float* __restrict__ offs,
    const float* __restrict__ aw, const float* __restrict__ refp,
    float* __restrict__ out)
{
  const int unit = blockIdx.x * 8 + (threadIdx.x >> 5);
  const int d = threadIdx.x & 31;
  const int h = unit & 7;
  const int row = unit >> 3;         // b*8192 + q
  const int b = row >> 13;
  const float* offr = offs + (size_t)row * 192 + h * 24;
  const float* awr  = aw   + (size_t)row * 96  + h * 12;
  const float* rp   = refp + (size_t)row * 6;
  const float* vb   = v + (size_t)b * 6300 * 256 + h * 32 + d;

  const int Hs[3] = {60, 30, 15}, Ws[3] = {80, 40, 20}, St[3] = {0, 4800, 6000};
  float acc = 0.f;
#pragma unroll
  for (int l = 0; l < 3; l++) {
    const float rx = rp[l * 2], ry = rp[l * 2 + 1];
    const int W = Ws[l], H = Hs[l];
    const float* vl = vb + (size_t)St[l] * 256;
#pragma unroll
    for (int p = 0; p < 4; p++) {
      const float gx = rx * W + offr[(l * 4 + p) * 2]     - 0.5f;
      const float gy = ry * H + offr[(l * 4 + p) * 2 + 1] - 0.5f;
      const float w  = awr[l * 4 + p];
      const float x0f = floorf(gx), y0f = floorf(gy);
      const float wx = gx - x0f, wy = gy - y0f;
      const int x0 = (int)x0f, y0 = (int)y0f;
      const float s00 = vfetch(vl, x0,     y0,     W, H);
      const float s10 = vfetch(vl, x0 + 1, y0,     W, H);
      const float s01 = vfetch(vl, x0,     y0 + 1, W, H);
      const float s11 = vfetch(vl, x0 + 1, y0 + 1, W, H);
      acc += w * ((s00 * (1.f - wx) + s10 * wx) * (1.f - wy) +
                  (s01 * (1.f - wx) + s11 * wx) * wy);
    }
  }
  out[(size_t)row * 256 + h * 32 + d] = acc;
}

// ---------------------------------------------------------------------------
// Launch
// ---------------------------------------------------------------------------
extern "C" void kernel_launch(void* const* d_in, const int* in_sizes, int n_in,
                              void* d_out, int out_size, void* d_ws, size_t ws_size,
                              hipStream_t stream)
{
  const float* query     = (const float*)d_in[0];
  const float* value     = (const float*)d_in[1];
  const float* query_pos = (const float*)d_in[2];
  const float* ref_pts   = (const float*)d_in[3];
  // d_in[4] spatial_shapes, d_in[5] level_start_index: hard-coded constants
  const float* g1  = (const float*)d_in[6];
  const float* b1  = (const float*)d_in[7];
  const float* Wo  = (const float*)d_in[8];
  const float* bo  = (const float*)d_in[9];
  const float* Wa  = (const float*)d_in[10];
  const float* ba  = (const float*)d_in[11];
  const float* Wv  = (const float*)d_in[12];
  const float* bv  = (const float*)d_in[13];
  const float* Wp  = (const float*)d_in[14];
  const float* bp  = (const float*)d_in[15];
  const float* g2  = (const float*)d_in[16];
  const float* b2  = (const float*)d_in[17];
  const float* Wf1 = (const float*)d_in[18];
  const float* bf1 = (const float*)d_in[19];
  const float* Wf2 = (const float*)d_in[20];
  const float* bf2 = (const float*)d_in[21];

  float* ws = (float*)d_ws;
  // Workspace layout (floats). hidden (16.78M) overlaps the dead
  // qn/qa/v/offs/aw region by FFN time.
  float* qn     = ws;                 // 4,194,304
  float* qa     = ws + 4194304;       // 4,194,304 (reused as `sampled` later)
  float* vbuf   = ws + 8388608;       // 3,225,600
  float* offs   = ws + 11614208;      // 3,145,728
  float* aw     = ws + 14759936;      // 1,572,864  (ends 16,332,800)
  float* hidden = ws;                 // 16,777,216 (overlaps all of the above)
  float* q2     = ws + 16777216;      // 4,194,304
  float* qbuf   = ws + 20971520;      // 4,194,304  (total 25,165,824 floats)
  float* sampled = qa;
  float* outp    = (float*)d_out;

  // 1. qn = LN(query); qa = qn + query_pos
  ln_kernel<<<4096, 256, 0, stream>>>(query, query_pos, g1, b1, qn, qa);
  // 2. offs = qa @ Wo + bo            [16384 x 192]
  gemm_kernel<0><<<dim3(3, 256), 256, 0, stream>>>(qa, Wo, bo, nullptr, nullptr,
                                                   offs, 16384, 192, 256);
  // 3. aw = qa @ Wa + ba              [16384 x 96]
  gemm_kernel<0><<<dim3(2, 256), 256, 0, stream>>>(qa, Wa, ba, nullptr, nullptr,
                                                   aw, 16384, 96, 256);
  // 4. softmax over 12 per (b,q,h), in place
  softmax12<<<512, 256, 0, stream>>>(aw);
  // 5. v = value @ Wv + bv            [12600 x 256]
  gemm_kernel<0><<<dim3(4, 197), 256, 0, stream>>>(value, Wv, bv, nullptr, nullptr,
                                                   vbuf, 12600, 256, 256);
  // 6. deformable sampling -> sampled [16384 x 256]
  deform_sample<<<16384, 256, 0, stream>>>(vbuf, offs, aw, ref_pts, sampled);
  // 7. q = sampled @ Wp + bp + qn + query
  gemm_kernel<2><<<dim3(4, 256), 256, 0, stream>>>(sampled, Wp, bp, qn, query,
                                                   qbuf, 16384, 256, 256);
  // 8. q2 = LN(q)
  ln_kernel<<<4096, 256, 0, stream>>>(qbuf, nullptr, g2, b2, q2, nullptr);
  // 9. hidden = gelu(q2 @ Wf1 + bf1)  [16384 x 1024]
  gemm_kernel<1><<<dim3(16, 256), 256, 0, stream>>>(q2, Wf1, bf1, nullptr, nullptr,
                                                    hidden, 16384, 1024, 256);
  // 10. out = q + hidden @ Wf2 + bf2
  gemm_kernel<3><<<dim3(4, 256), 256, 0, stream>>>(hidden, Wf2, bf2, qbuf, nullptr,
                                                   outp, 16384, 256, 1024);
}